// Round 2
// baseline (719.110 us; speedup 1.0000x reference)
//
#include <hip/hip_runtime.h>
#include <hip/hip_bf16.h>

typedef unsigned long long u64;

static constexpr int NF = 27552;              // 2*13776 faces
static constexpr int IMGOFF = 3 * 256 * 256;  // image elements before textures

#define EYEZ 2.7320508075688772f   // -(EYE.z) = 1/tan(30deg)+1, fp64->fp32

// ---------------------------------------------------------------------------
// Kernel 1: per-face rasterization constants + cull bbox
// fdat[f*16]: a0,a1,a2,b0,b1,b2,c0,c1,c2,det_safe,iz0,iz1,iz2,z0,z1,z2
// fbb[f]: minx,maxx,miny,maxy (empty box if back-facing)
// All fp ops replicate numpy's op order exactly (no FMA contraction) so the
// per-pixel depth argmin is bit-identical to the fp32 reference.
// ---------------------------------------------------------------------------
__global__ __launch_bounds__(256) void face_prep(
    const float* __restrict__ cam,
    const float* __restrict__ verts,
    const int* __restrict__ faces,
    float* __restrict__ fdat,
    float4* __restrict__ fbb)
{
    int f = blockIdx.x * 256 + threadIdx.x;
    if (f >= NF) return;
    float c0 = cam[0], c1 = cam[1], c2 = cam[2];
    // replicate np look_at rounding exactly: z3 = E/sqrt(E*E); x0=z3/sqrt(z3^2);
    // y1 = (z3*x0)/sqrt((z3*x0)^2).  (These are 1.0 in binary FP, but free.)
    float z3 = __fdiv_rn(EYEZ, __fsqrt_rn(__fmul_rn(EYEZ, EYEZ)));
    float x0r = __fdiv_rn(z3, __fsqrt_rn(__fmul_rn(z3, z3)));
    float wyy = __fmul_rn(z3, x0r);
    float y1r = __fdiv_rn(wyy, __fsqrt_rn(__fmul_rn(wyy, wyy)));

    float xs[3], ys[3], zs[3];
#pragma unroll
    for (int i = 0; i < 3; i++) {
        int vi = faces[f * 3 + i];
        float vx = verts[vi * 3 + 0];
        float vy = verts[vi * 3 + 1];
        float vz = verts[vi * 3 + 2];
        float px = __fmul_rn(c0, __fadd_rn(vx, c1));
        float py = __fmul_rn(c0, __fadd_rn(vy, c2));
        xs[i] = __fmul_rn(px, x0r);
        ys[i] = __fmul_rn(-py, y1r);
        zs[i] = __fmul_rn(__fadd_rn(vz, EYEZ), z3);
    }
    float a0 = __fsub_rn(ys[1], ys[2]);
    float a1 = __fsub_rn(ys[2], ys[0]);
    float a2 = __fsub_rn(ys[0], ys[1]);
    float b0 = __fsub_rn(xs[2], xs[1]);
    float b1 = __fsub_rn(xs[0], xs[2]);
    float b2 = __fsub_rn(xs[1], xs[0]);
    float cc0 = __fsub_rn(__fmul_rn(xs[1], ys[2]), __fmul_rn(xs[2], ys[1]));
    float cc1 = __fsub_rn(__fmul_rn(xs[2], ys[0]), __fmul_rn(xs[0], ys[2]));
    float cc2 = __fsub_rn(__fmul_rn(xs[0], ys[1]), __fmul_rn(xs[1], ys[0]));
    float det = __fadd_rn(__fadd_rn(cc0, cc1), cc2);
    float ds  = (fabsf(det) > 1e-10f) ? det : 1e-10f;
    float z0 = (fabsf(zs[0]) > 1e-6f) ? zs[0] : 1e-6f;
    float z1 = (fabsf(zs[1]) > 1e-6f) ? zs[1] : 1e-6f;
    float z2 = (fabsf(zs[2]) > 1e-6f) ? zs[2] : 1e-6f;

    float* o = fdat + (size_t)f * 16;
    o[0] = a0; o[1] = a1; o[2] = a2;
    o[3] = b0; o[4] = b1; o[5] = b2;
    o[6] = cc0; o[7] = cc1; o[8] = cc2;
    o[9] = ds;
    o[10] = __fdiv_rn(1.0f, z0);
    o[11] = __fdiv_rn(1.0f, z1);
    o[12] = __fdiv_rn(1.0f, z2);
    o[13] = z0; o[14] = z1; o[15] = z2;

    float4 bb;
    if (det > 0.0f) {  // back faces can never be `valid` -> exact cull
        bb.x = fminf(fminf(xs[0], xs[1]), xs[2]) - 1e-4f;
        bb.y = fmaxf(fmaxf(xs[0], xs[1]), xs[2]) + 1e-4f;
        bb.z = fminf(fminf(ys[0], ys[1]), ys[2]) - 1e-4f;
        bb.w = fmaxf(fmaxf(ys[0], ys[1]), ys[2]) + 1e-4f;
    } else {
        bb.x = 3e30f; bb.y = -3e30f; bb.z = 3e30f; bb.w = -3e30f;
    }
    fbb[f] = bb;
}

// ---------------------------------------------------------------------------
// Kernel 2: 9 bilinear texture samples per face -> textures output (fp32).
// lighting() is the identity (DIR_INT=0, AMB=1).  3rd TS dim is broadcast.
// Rasterizer reads these values back from d_out (same fp32 values).
// ---------------------------------------------------------------------------
__global__ __launch_bounds__(256) void tex_sample(
    const float* __restrict__ cam,
    const float* __restrict__ verts,
    const int* __restrict__ faces,
    const float* __restrict__ uv,
    float* __restrict__ out_tex)
{
    int id = blockIdx.x * 256 + threadIdx.x;
    if (id >= NF * 9) return;
    int f = id / 9, t = id - f * 9;
    float c0 = cam[0], c1 = cam[1], c2 = cam[2];
    float px[3], py[3];
#pragma unroll
    for (int i = 0; i < 3; i++) {
        int vi = faces[f * 3 + i];
        px[i] = __fmul_rn(c0, __fadd_rn(verts[vi * 3 + 0], c1));
        py[i] = __fmul_rn(c0, __fadd_rn(verts[vi * 3 + 1], c2));
    }
    const float abv[3] = {0.0f, 0.5f, 1.0f};
    int t1 = t / 3, t2 = t - t1 * 3;
    float uu = abv[t1], vv = abv[t2];
    // s = (p0-p2)*u + (p1-p2)*v + p2   (einsum order, then + v2)
    float sx = __fadd_rn(__fadd_rn(__fmul_rn(__fsub_rn(px[0], px[2]), uu),
                                   __fmul_rn(__fsub_rn(px[1], px[2]), vv)), px[2]);
    float sy = __fadd_rn(__fadd_rn(__fmul_rn(__fsub_rn(py[0], py[2]), uu),
                                   __fmul_rn(__fsub_rn(py[1], py[2]), vv)), py[2]);
    sx = fminf(fmaxf(sx, -1.0f), 1.0f);
    sy = fminf(fmaxf(sy, -1.0f), 1.0f);
    float xg = __fmul_rn(__fmul_rn(__fadd_rn(sx, 1.0f), 0.5f), 255.0f);
    float yg = __fmul_rn(__fmul_rn(__fadd_rn(sy, 1.0f), 0.5f), 255.0f);
    float x0f = floorf(xg), y0f = floorf(yg);
    float wx = __fsub_rn(xg, x0f), wy = __fsub_rn(yg, y0f);
    int x0 = (int)x0f; x0 = x0 < 0 ? 0 : (x0 > 255 ? 255 : x0);
    int y0 = (int)y0f; y0 = y0 < 0 ? 0 : (y0 > 255 ? 255 : y0);
    int x1 = x0 + 1 > 255 ? 255 : x0 + 1;
    int y1 = y0 + 1 > 255 ? 255 : y0 + 1;
    float omwx = __fsub_rn(1.0f, wx), omwy = __fsub_rn(1.0f, wy);
    float w00 = __fmul_rn(omwx, omwy);
    float w10 = __fmul_rn(wx, omwy);
    float w01 = __fmul_rn(omwx, wy);
    float w11 = __fmul_rn(wx, wy);
    size_t tb = (size_t)f * 81 + (size_t)t1 * 27 + (size_t)t2 * 9;
#pragma unroll
    for (int c = 0; c < 3; c++) {
        const float* img = uv + c * 65536;
        float g00 = img[y0 * 256 + x0];
        float g10 = img[y0 * 256 + x1];
        float g01 = img[y1 * 256 + x0];
        float g11 = img[y1 * 256 + x1];
        float val = __fmul_rn(g00, w00);
        val = __fadd_rn(val, __fmul_rn(g10, w10));
        val = __fadd_rn(val, __fmul_rn(g01, w01));
        val = __fadd_rn(val, __fmul_rn(g11, w11));
        out_tex[tb + 0 + c] = val;   // k = 0,1,2 broadcast
        out_tex[tb + 3 + c] = val;
        out_tex[tb + 6 + c] = val;
    }
}

// ---------------------------------------------------------------------------
// Kernel 3: rasterizer. 1024 blocks = 32x32 tiles of 8x8 pixels.
// 256 threads = 4 face-subgroups x 64 pixels. Chunked LDS staging with
// bbox compaction; argmin as packed (depth_bits<<32)|face_id u64 min
// (== numpy first-index tie-break). All fp ops in numpy's exact order.
// ---------------------------------------------------------------------------
__global__ __launch_bounds__(256) void raster(
    const float* __restrict__ fdat,
    const float4* __restrict__ fbb,
    const float* __restrict__ tex,   // = d_out + IMGOFF, written by tex_sample
    float* __restrict__ out_img)
{
    __shared__ __align__(16) float sdata[256 * 16];
    __shared__ int sids[256];
    __shared__ int scount;
    __shared__ u64 sbest[256];
    const int tid = threadIdx.x;
    const int tile = blockIdx.x;
    const int tx = tile & 31, ty = tile >> 5;
    const int p = tid & 63, g = tid >> 6;
    const int pxi = tx * 8 + (p & 7), pyi = ty * 8 + (p >> 3);
    const float xp = (float)(2 * pxi + 1 - 256) * (1.0f / 256.0f);  // exact
    const float yp = (float)(2 * pyi + 1 - 256) * (1.0f / 256.0f);
    const float xlo = (float)(2 * (tx * 8) + 1 - 256) * (1.0f / 256.0f);
    const float xhi = (float)(2 * (tx * 8 + 7) + 1 - 256) * (1.0f / 256.0f);
    const float ylo = (float)(2 * (ty * 8) + 1 - 256) * (1.0f / 256.0f);
    const float yhi = (float)(2 * (ty * 8 + 7) + 1 - 256) * (1.0f / 256.0f);

    u64 best = ((u64)0x42C80000u << 32);  // depth FAR=100.0f, idx 0

    for (int base = 0; base < NF; base += 256) {
        __syncthreads();
        if (tid == 0) scount = 0;
        __syncthreads();
        int fi = base + tid;
        if (fi < NF) {
            float4 bb = fbb[fi];
            if (bb.x <= xhi && bb.y >= xlo && bb.z <= yhi && bb.w >= ylo) {
                int pos = atomicAdd(&scount, 1);
                sids[pos] = fi;
            }
        }
        __syncthreads();
        const int n = scount;
        for (int j = tid; j < n * 4; j += 256) {
            int s = j >> 2, q = j & 3;
            ((float4*)sdata)[s * 4 + q] =
                ((const float4*)(fdat + (size_t)sids[s] * 16))[q];
        }
        __syncthreads();
        for (int s = g; s < n; s += 4) {
            const float* fd = sdata + s * 16;
            float t0 = __fadd_rn(__fadd_rn(__fmul_rn(xp, fd[0]), __fmul_rn(yp, fd[3])), fd[6]);
            float t1 = __fadd_rn(__fadd_rn(__fmul_rn(xp, fd[1]), __fmul_rn(yp, fd[4])), fd[7]);
            float t2 = __fadd_rn(__fadd_rn(__fmul_rn(xp, fd[2]), __fmul_rn(yp, fd[5])), fd[8]);
            // staged faces have det_safe>0 => sign(w)==sign(t): exact w>=0 test
            if (t0 < 0.0f || t1 < 0.0f || t2 < 0.0f) continue;
            float dsf = fd[9];
            float w0 = __fdiv_rn(t0, dsf), w1 = __fdiv_rn(t1, dsf), w2 = __fdiv_rn(t2, dsf);
            if (w0 > 1.0f || w1 > 1.0f || w2 > 1.0f) continue;
            float den = __fmul_rn(w0, fd[10]);
            den = __fadd_rn(den, __fmul_rn(w1, fd[11]));
            den = __fadd_rn(den, __fmul_rn(w2, fd[12]));
            if (den > 1e-8f) {
                float zp = __fdiv_rn(1.0f, den);
                if (zp > 0.1f && zp < 100.0f) {
                    u64 cand = ((u64)__float_as_uint(zp) << 32) | (unsigned)sids[s];
                    if (cand < best) best = cand;
                }
            }
        }
    }
    sbest[tid] = best;
    __syncthreads();
    if (tid < 64) {
        u64 m = sbest[tid];
        u64 m1 = sbest[64 + tid];  if (m1 < m) m = m1;
        u64 m2 = sbest[128 + tid]; if (m2 < m) m = m2;
        u64 m3 = sbest[192 + tid]; if (m3 < m) m = m3;
        float col0 = 0.f, col1 = 0.f, col2 = 0.f;
        float depth = __uint_as_float((unsigned)(m >> 32));
        if (depth < 100.0f) {
            int fidx = (int)(unsigned)(m & 0xFFFFFFFFu);
            const float* fd = fdat + (size_t)fidx * 16;
            float t0 = __fadd_rn(__fadd_rn(__fmul_rn(xp, fd[0]), __fmul_rn(yp, fd[3])), fd[6]);
            float t1 = __fadd_rn(__fadd_rn(__fmul_rn(xp, fd[1]), __fmul_rn(yp, fd[4])), fd[7]);
            float t2 = __fadd_rn(__fadd_rn(__fmul_rn(xp, fd[2]), __fmul_rn(yp, fd[5])), fd[8]);
            float dsf = fd[9];
            float w0 = __fdiv_rn(t0, dsf), w1 = __fdiv_rn(t1, dsf), w2 = __fdiv_rn(t2, dsf);
            float wc0 = __fdiv_rn(w0, fd[13]);
            float wc1 = __fdiv_rn(w1, fd[14]);
            float wc2 = __fdiv_rn(w2, fd[15]);
            float ssum = __fadd_rn(__fadd_rn(wc0, wc1), wc2);
            float dnm = fmaxf(ssum, 1e-8f);
            wc0 = __fdiv_rn(wc0, dnm); wc1 = __fdiv_rn(wc1, dnm); wc2 = __fdiv_rn(wc2, dnm);
            float pos0 = __fmul_rn(fminf(fmaxf(wc0, 0.f), 1.f), 2.0f);
            float pos1 = __fmul_rn(fminf(fmaxf(wc1, 0.f), 1.f), 2.0f);
            float lf0 = fminf(fmaxf(floorf(pos0), 0.f), 2.f);
            float lf1 = fminf(fmaxf(floorf(pos1), 0.f), 2.f);
            float pos2 = __fmul_rn(fminf(fmaxf(wc2, 0.f), 1.f), 2.0f);
            float lf2 = fminf(fmaxf(floorf(pos2), 0.f), 2.f);
            float fr0 = __fsub_rn(pos0, lf0), fr1 = __fsub_rn(pos1, lf1), fr2 = __fsub_rn(pos2, lf2);
            int lo0 = (int)lf0, lo1 = (int)lf1;
            int hi0 = lo0 + 1 > 2 ? 2 : lo0 + 1;
            int hi1 = lo1 + 1 > 2 ? 2 : lo1 + 1;
            const float* tbase = tex + (size_t)fidx * 81;
#pragma unroll
            for (int bits = 0; bits < 8; bits++) {
                int u0 = bits & 1, u1 = (bits >> 1) & 1, u2 = (bits >> 2) & 1;
                int i0 = u0 ? hi0 : lo0;
                int i1 = u1 ? hi1 : lo1;
                float e0 = u0 ? fr0 : __fsub_rn(1.0f, fr0);
                float e1 = u1 ? fr1 : __fsub_rn(1.0f, fr1);
                float e2 = u2 ? fr2 : __fsub_rn(1.0f, fr2);
                float wgt = __fmul_rn(__fmul_rn(e0, e1), e2);
                // textures layout f*81 + i0*27 + i1*9 + k*3 + c; k broadcast -> k=0
                const float* tp = tbase + (size_t)i0 * 27 + (size_t)i1 * 9;
                col0 = __fadd_rn(col0, __fmul_rn(wgt, tp[0]));
                col1 = __fadd_rn(col1, __fmul_rn(wgt, tp[1]));
                col2 = __fadd_rn(col2, __fmul_rn(wgt, tp[2]));
            }
        }
        int xo = tx * 8 + (tid & 7), yo = ty * 8 + (tid >> 3);
        size_t pix = (size_t)yo * 256 + xo;
        out_img[pix]          = col0;
        out_img[65536 + pix]  = col1;
        out_img[131072 + pix] = col2;
    }
}

extern "C" void kernel_launch(void* const* d_in, const int* in_sizes, int n_in,
                              void* d_out, int out_size, void* d_ws, size_t ws_size,
                              hipStream_t stream) {
    const float* cam   = (const float*)d_in[0];
    const float* verts = (const float*)d_in[1];
    const float* uv    = (const float*)d_in[2];
    const int*   faces = (const int*)d_in[3];
    float* out = (float*)d_out;

    float*  fdat = (float*)d_ws;                       // NF*16 floats
    float4* fbb  = (float4*)(fdat + (size_t)NF * 16);  // NF*4 floats

    float* out_img = out;            // 3*256*256
    float* out_tex = out + IMGOFF;   // NF*81

    hipLaunchKernelGGL(face_prep, dim3((NF + 255) / 256), dim3(256), 0, stream,
                       cam, verts, faces, fdat, fbb);
    hipLaunchKernelGGL(tex_sample, dim3((NF * 9 + 255) / 256), dim3(256), 0, stream,
                       cam, verts, faces, uv, out_tex);
    hipLaunchKernelGGL(raster, dim3(1024), dim3(256), 0, stream,
                       fdat, fbb, out_tex, out_img);
}